// Round 17
// baseline (616.589 us; speedup 1.0000x reference)
//
#include <hip/hip_runtime.h>

typedef __bf16 bf16x8 __attribute__((ext_vector_type(8)));
typedef float  f32x4  __attribute__((ext_vector_type(4)));
typedef float  fvec4  __attribute__((ext_vector_type(4)));

#define NSPEC 8
#define NB    65536
#define NF    256

// ---------------------------------------------------------------------------
// Prologue: W[l][s][in][out] f32  ->  WT[l][s][out][in] bf16   (3 MB in d_ws)
// ---------------------------------------------------------------------------
__global__ __launch_bounds__(256) void wconv_kernel(
    const float* __restrict__ W1, const float* __restrict__ W2,
    const float* __restrict__ W3, __bf16* __restrict__ WT)
{
    __shared__ float tile[32][33];
    int bid = blockIdx.x;
    int l   = bid >> 9;
    int rem = bid & 511;
    int s   = rem >> 6;
    int tt  = rem & 63;
    int ti  = tt >> 3, tj = tt & 7;
    const float* W   = (l == 0) ? W1 : (l == 1) ? W2 : W3;
    const float* ibs = W + (size_t)s * 65536;
    int c  = threadIdx.x & 31;
    int r0 = threadIdx.x >> 5;
#pragma unroll
    for (int k = 0; k < 4; ++k) {
        int r = r0 + k * 8;
        tile[r][c] = ibs[(ti * 32 + r) * 256 + tj * 32 + c];
    }
    __syncthreads();
    __bf16* obs = WT + ((size_t)(l * 8 + s)) * 65536;
#pragma unroll
    for (int k = 0; k < 4; ++k) {
        int r = r0 + k * 8;
        obs[(tj * 32 + r) * 256 + ti * 32 + c] = (__bf16)tile[c][r];
    }
}

// async global->LDS, 16B per lane, literal size (required)
#define GLLD(gp, lp)                                                     \
    __builtin_amdgcn_global_load_lds(                                    \
        (const __attribute__((address_space(1))) char*)(gp),             \
        (__attribute__((address_space(3))) char*)(lp), 16, 0, 0)

// full barrier WITHOUT vmcnt drain: weight prefetch survives.
#define BAR()                                                            \
    do {                                                                 \
        __builtin_amdgcn_sched_barrier(0);                               \
        asm volatile("s_waitcnt lgkmcnt(0)" ::: "memory");               \
        __builtin_amdgcn_s_barrier();                                    \
        __builtin_amdgcn_sched_barrier(0);                               \
    } while (0)

#define ISSUE_CHUNK(wtb, gci)                                            \
    do {                                                                 \
        char* lp0 = (char*)&wlds[(gci) % 3][wave * 4096];                \
        GLLD((wtb) + gll_off[0] + ((gci) & 7) * 64, lp0);                \
        GLLD((wtb) + gll_off[1] + ((gci) & 7) * 64, lp0 + 1024);         \
        GLLD((wtb) + gll_off[2] + ((gci) & 7) * 64, lp0 + 2048);         \
        GLLD((wtb) + gll_off[3] + ((gci) & 7) * 64, lp0 + 3072);         \
    } while (0)

#define READ_SET(AF, BF, gci, kslice)                                    \
    do {                                                                 \
        const char* wbuf_ = (const char*)wlds[(gci) % 3];                \
        _Pragma("unroll")                                                \
        for (int m_ = 0; m_ < 4; ++m_) {                                 \
            int row_ = wv + m_ * 16 + l15;                               \
            AF[m_] = *(const bf16x8*)(wbuf_ + row_ * 64 +                \
                                      ((g ^ ((row_ >> 1) & 3)) << 4));   \
        }                                                                \
        _Pragma("unroll")                                                \
        for (int n_ = 0; n_ < 4; ++n_)                                   \
            BF[n_] = *(const bf16x8*)(pA + (n_ * 16 + l15) * 512 +       \
                                      (((kslice) * 64 + g * 16) ^ swzB));\
    } while (0)

#define MFMA_SET(AF, BF)                                                 \
    do {                                                                 \
        __builtin_amdgcn_s_setprio(1);                                   \
        _Pragma("unroll")                                                \
        for (int m_ = 0; m_ < 4; ++m_)                                   \
            _Pragma("unroll")                                            \
            for (int n_ = 0; n_ < 4; ++n_)                               \
                acc[m_][n_] = __builtin_amdgcn_mfma_f32_16x16x32_bf16(   \
                    AF[m_], BF[n_], acc[m_][n_], 0, 0, 0);               \
        __builtin_amdgcn_s_setprio(0);                                   \
    } while (0)

// keep-alive sink: forces the 8 fragment loads to occur & complete (rule 17)
#define KEEP_SET(AF, BF)                                                 \
    asm volatile("" :: "v"(AF[0]), "v"(AF[1]), "v"(AF[2]), "v"(AF[3]),   \
                       "v"(BF[0]), "v"(BF[1]), "v"(BF[2]), "v"(BF[3]))

#define MLP_BODY(DO_MFMA, POUT)                                          \
    __shared__ __align__(16) __bf16 act[64 * 256];                       \
    __shared__ __align__(16) char  wlds[3][16384];                       \
    const int t    = threadIdx.x;                                        \
    const int lane = t & 63;                                             \
    const int wave = t >> 6;                                             \
    const int l15  = lane & 15;                                          \
    const int g    = lane >> 4;                                          \
    const int wv   = wave * 64;                                          \
    const int s    = blockIdx.x >> 10;                                   \
    const int row0 = (blockIdx.x & 1023) * 64;                           \
    const int swzB = l15 << 4;                                           \
    char* const pA = (char*)act;                                         \
    int gll_off[4];                                                      \
    _Pragma("unroll")                                                    \
    for (int i = 0; i < 4; ++i) {                                        \
        int v = wv + i * 16 + (lane >> 2);                               \
        int q = (lane & 3) ^ ((v >> 1) & 3);                             \
        gll_off[i] = v * 512 + q * 16;                                   \
    }                                                                    \
    const char* const wt0 = (const char*)(WT + ((size_t)(0 * 8 + s) << 16)); \
    const char* const wt1 = (const char*)(WT + ((size_t)(1 * 8 + s) << 16)); \
    const char* const wt2 = (const char*)(WT + ((size_t)(2 * 8 + s) << 16)); \
    fvec4 bias[3][4];                                                    \
    _Pragma("unroll")                                                    \
    for (int l = 0; l < 3; ++l) {                                        \
        const float* bl = (l == 0 ? b1 : l == 1 ? b2 : b3) + s * 256;    \
        _Pragma("unroll")                                                \
        for (int m = 0; m < 4; ++m)                                      \
            bias[l][m] = *(const fvec4*)(bl + wv + m * 16 + g * 4);      \
    }                                                                    \
    const float* src = bIn + ((size_t)s * NB + row0) * NF;               \
    _Pragma("unroll")                                                    \
    for (int it = 0; it < 16; ++it) {                                    \
        int flat = it * 1024 + t * 4;                                    \
        int r = flat >> 8;                                               \
        int f = flat & 255;                                              \
        fvec4 v = __builtin_nontemporal_load((const fvec4*)(src + flat));\
        union { __bf16 h[4]; unsigned long long q; } pk;                 \
        pk.h[0] = (__bf16)v[0]; pk.h[1] = (__bf16)v[1];                  \
        pk.h[2] = (__bf16)v[2]; pk.h[3] = (__bf16)v[3];                  \
        *(unsigned long long*)(pA + r * 512 + ((f * 2) ^ ((r & 15) << 4))) = pk.q; \
    }                                                                    \
    ISSUE_CHUNK(wt0, 0);                                                 \
    ISSUE_CHUNK(wt0, 1);                                                 \
    ISSUE_CHUNK(wt0, 2);                                                 \
    BAR();                                                               \
    _Pragma("unroll")                                                    \
    for (int l = 0; l < 3; ++l) {                                        \
        const int c0 = l * 8;                                            \
        f32x4 acc[4][4];                                                 \
        _Pragma("unroll")                                                \
        for (int m = 0; m < 4; ++m)                                      \
            _Pragma("unroll")                                            \
            for (int n = 0; n < 4; ++n)                                  \
                acc[m][n] = (f32x4){0.f, 0.f, 0.f, 0.f};                 \
        bf16x8 afX[4], bfX[4], afY[4], bfY[4];                           \
        asm volatile("s_waitcnt vmcnt(8)" ::: "memory");                 \
        READ_SET(afX, bfX, c0, 0);                                       \
        _Pragma("unroll")                                                \
        for (int ks = 0; ks < 8; ++ks) {                                 \
            const int c = c0 + ks;                                       \
            if (ks < 7) {                                                \
                if (c <= 21) asm volatile("s_waitcnt vmcnt(4)" ::: "memory"); \
                else         asm volatile("s_waitcnt vmcnt(0)" ::: "memory"); \
                if ((ks & 1) == 0) READ_SET(afY, bfY, c + 1, ks + 1);    \
                else               READ_SET(afX, bfX, c + 1, ks + 1);    \
                asm volatile("s_waitcnt lgkmcnt(8)" ::: "memory");       \
            } else {                                                     \
                asm volatile("s_waitcnt lgkmcnt(0)" ::: "memory");       \
            }                                                            \
            const int gci = c + 3;                                       \
            if (gci <= 23) {                                             \
                const char* wtc = (gci < 8) ? wt0 : (gci < 16) ? wt1 : wt2; \
                ISSUE_CHUNK(wtc, gci);                                   \
            }                                                            \
            __builtin_amdgcn_sched_barrier(0);                           \
            if (DO_MFMA) {                                               \
                if ((ks & 1) == 0) MFMA_SET(afX, bfX);                   \
                else               MFMA_SET(afY, bfY);                   \
            } else {                                                     \
                if ((ks & 1) == 0) KEEP_SET(afX, bfX);                   \
                else               KEEP_SET(afY, bfY);                   \
            }                                                            \
            __builtin_amdgcn_sched_barrier(0);                           \
        }                                                                \
        BAR();                                                           \
        _Pragma("unroll")                                                \
        for (int m = 0; m < 4; ++m) {                                    \
            int vbyte = (wv + m * 16 + g * 4) * 2;                       \
            _Pragma("unroll")                                            \
            for (int n = 0; n < 4; ++n) {                                \
                union { __bf16 h[4]; unsigned long long q; } pk;         \
                _Pragma("unroll")                                        \
                for (int j = 0; j < 4; ++j) {                            \
                    float x = acc[m][n][j] + bias[l][m][j];              \
                    x = (x >= 0.f) ? x : 0.1f * x;                       \
                    pk.h[j] = (__bf16)x;                                 \
                }                                                        \
                *(unsigned long long*)(pA + (n * 16 + l15) * 512 + (vbyte ^ swzB)) = pk.q; \
            }                                                            \
        }                                                                \
        BAR();                                                           \
    }                                                                    \
    const int r4   = t >> 2;                                             \
    const int u0   = (t & 3) * 64;                                       \
    const int swz4 = (r4 & 15) << 4;                                     \
    const float* w4s = W4 + s * 256 + u0;                                \
    float part = 0.f;                                                    \
    _Pragma("unroll")                                                    \
    for (int i = 0; i < 8; ++i) {                                        \
        bf16x8 x = *(const bf16x8*)(pA + r4 * 512 + (((u0 + i * 8) * 2) ^ swz4)); \
        fvec4 wlo = *(const fvec4*)(w4s + i * 8);                        \
        fvec4 whi = *(const fvec4*)(w4s + i * 8 + 4);                    \
        part += (float)x[0] * wlo[0] + (float)x[1] * wlo[1] +            \
                (float)x[2] * wlo[2] + (float)x[3] * wlo[3] +            \
                (float)x[4] * whi[0] + (float)x[5] * whi[1] +            \
                (float)x[6] * whi[2] + (float)x[7] * whi[3];             \
    }                                                                    \
    part += __shfl_xor(part, 1);                                         \
    part += __shfl_xor(part, 2);                                         \
    if ((t & 3) == 0) POUT[(size_t)s * NB + row0 + r4] = part + b4[s];

// ---------------------------------------------------------------------------
// Real kernel (r15-best, 327.8us) and the no-MFMA ablation twin.
// ---------------------------------------------------------------------------
__global__ __launch_bounds__(256, 2) void mlp_full(
    const float* __restrict__ bIn, const float* __restrict__ b1,
    const float* __restrict__ b2,  const float* __restrict__ b3,
    const float* __restrict__ W4,  const float* __restrict__ b4,
    const __bf16* __restrict__ WT, float* __restrict__ P)
{
    MLP_BODY(1, P)
}

__global__ __launch_bounds__(256, 2) void mlp_nomfma(
    const float* __restrict__ bIn, const float* __restrict__ b1,
    const float* __restrict__ b2,  const float* __restrict__ b3,
    const float* __restrict__ W4,  const float* __restrict__ b4,
    const __bf16* __restrict__ WT, float* __restrict__ Pd)
{
    MLP_BODY(0, Pd)
}

// ---------------------------------------------------------------------------
// Final: out[i] = sigmoid(sum_s P[s][i])
// ---------------------------------------------------------------------------
__global__ __launch_bounds__(256) void reduce_kernel(
    const float* __restrict__ P, float* __restrict__ out)
{
    int i = blockIdx.x * 256 + threadIdx.x;
    float a = 0.f;
#pragma unroll
    for (int sp = 0; sp < NSPEC; ++sp) a += P[(size_t)sp * NB + i];
    out[i] = 1.f / (1.f + __expf(-a));
}

extern "C" void kernel_launch(void* const* d_in, const int* in_sizes, int n_in,
                              void* d_out, int out_size, void* d_ws, size_t ws_size,
                              hipStream_t stream)
{
    const float* bIn = (const float*)d_in[0];
    const float* W1  = (const float*)d_in[1];
    const float* b1  = (const float*)d_in[2];
    const float* W2  = (const float*)d_in[3];
    const float* b2  = (const float*)d_in[4];
    const float* W3  = (const float*)d_in[5];
    const float* b3  = (const float*)d_in[6];
    const float* W4  = (const float*)d_in[7];
    const float* b4  = (const float*)d_in[8];
    __bf16* WT = (__bf16*)d_ws;                       // 3 MB
    float*  P  = (float*)((char*)d_ws + (3u << 20));  // 2 MB partials
    float*  Pd = P + (size_t)NSPEC * NB;              // 2 MB ablation dump

    wconv_kernel<<<1536, 256, 0, stream>>>(W1, W2, W3, WT);
    mlp_nomfma<<<8192, 256, 0, stream>>>(bIn, b1, b2, b3, W4, b4, WT, Pd);
    mlp_full  <<<8192, 256, 0, stream>>>(bIn, b1, b2, b3, W4, b4, WT, P);
    reduce_kernel<<<NB / 256, 256, 0, stream>>>(P, (float*)d_out);
}

// Round 18
// 458.165 us; speedup vs baseline: 1.3458x; 1.3458x over previous
//
#include <hip/hip_runtime.h>

typedef __bf16 bf16x8 __attribute__((ext_vector_type(8)));
typedef float  f32x4  __attribute__((ext_vector_type(4)));
typedef float  fvec4  __attribute__((ext_vector_type(4)));

#define NSPEC 8
#define NB    65536
#define NF    256

// ---------------------------------------------------------------------------
// Prologue: W[l][s][in][out] f32  ->  WT[l][s][out][in] bf16   (3 MB in d_ws)
// ---------------------------------------------------------------------------
__global__ __launch_bounds__(256) void wconv_kernel(
    const float* __restrict__ W1, const float* __restrict__ W2,
    const float* __restrict__ W3, __bf16* __restrict__ WT)
{
    __shared__ float tile[32][33];
    int bid = blockIdx.x;
    int l   = bid >> 9;
    int rem = bid & 511;
    int s   = rem >> 6;
    int tt  = rem & 63;
    int ti  = tt >> 3, tj = tt & 7;
    const float* W   = (l == 0) ? W1 : (l == 1) ? W2 : W3;
    const float* ibs = W + (size_t)s * 65536;
    int c  = threadIdx.x & 31;
    int r0 = threadIdx.x >> 5;
#pragma unroll
    for (int k = 0; k < 4; ++k) {
        int r = r0 + k * 8;
        tile[r][c] = ibs[(ti * 32 + r) * 256 + tj * 32 + c];
    }
    __syncthreads();
    __bf16* obs = WT + ((size_t)(l * 8 + s)) * 65536;
#pragma unroll
    for (int k = 0; k < 4; ++k) {
        int r = r0 + k * 8;
        obs[(tj * 32 + r) * 256 + ti * 32 + c] = (__bf16)tile[c][r];
    }
}

// full barrier WITHOUT vmcnt drain: in-flight ring loads survive.
#define BAR()                                                            \
    do {                                                                 \
        __builtin_amdgcn_sched_barrier(0);                               \
        asm volatile("s_waitcnt lgkmcnt(0)" ::: "memory");               \
        __builtin_amdgcn_s_barrier();                                    \
        __builtin_amdgcn_sched_barrier(0);                               \
    } while (0)

// ---------------------------------------------------------------------------
// Fused MLP, species-split. Weights stream GLOBAL->VGPR via inline-asm
// global_load_dwordx4 into a depth-3 register ring (asm "=v" outputs force
// allocation -- fixes r16 where the compiler dropped the ring at VGPR cap).
// Removes ALL weight LDS transit (was 58% of the LDS-pipe-bound 238us
// scaffold measured by r17's ablation). Counted vmcnt(8/4/0) + rule-18
// sched_barrier guarantee chunk arrival before its MFMAs. LDS = 32KB act.
// ---------------------------------------------------------------------------
__global__ __launch_bounds__(256) void mlp_kernel(
    const float* __restrict__ bIn, const float* __restrict__ b1,
    const float* __restrict__ b2,  const float* __restrict__ b3,
    const float* __restrict__ W4,  const float* __restrict__ b4,
    const __bf16* __restrict__ WT, float* __restrict__ P)
{
    __shared__ __align__(16) __bf16 act[64 * 256];   // 32 KB act, in-place

    const int t    = threadIdx.x;
    const int lane = t & 63;
    const int wave = t >> 6;          // 0..3, owns v-range [wave*64, wave*64+64)
    const int l15  = lane & 15;
    const int g    = lane >> 4;       // 0..3
    const int wv   = wave * 64;
    const int s    = blockIdx.x >> 10;
    const int row0 = (blockIdx.x & 1023) * 64;
    const int swzB = l15 << 4;
    char* const pA = (char*)act;

    // per-lane weight byte offsets within a layer's 64KB WT block:
    // row (wv+m*16+l15) * 512B + k-group g*16B ; chunk adds (c&7)*64B.
    unsigned woff[4];
#pragma unroll
    for (int m = 0; m < 4; ++m)
        woff[m] = (unsigned)((wv + m * 16 + l15) * 512 + g * 16);

    const char* wbase[3];
    wbase[0] = (const char*)(WT + ((size_t)(0 * 8 + s) << 16));
    wbase[1] = (const char*)(WT + ((size_t)(1 * 8 + s) << 16));
    wbase[2] = (const char*)(WT + ((size_t)(2 * 8 + s) << 16));

    bf16x8 wreg[3][4];

// issue the 4 asm loads of chunk gci into ring slot (gci%3); gci is a
// compile-time constant at every expansion (loops fully unrolled).
#define WLOAD(gci)                                                       \
    do {                                                                 \
        const char* wb_ = wbase[(gci) >> 3];                             \
        _Pragma("unroll")                                                \
        for (int m_ = 0; m_ < 4; ++m_) {                                 \
            const char* ap_ = wb_ + woff[m_] + ((gci) & 7) * 64;         \
            asm volatile("global_load_dwordx4 %0, %1, off"               \
                         : "=v"(wreg[(gci) % 3][m_]) : "v"(ap_));        \
        }                                                                \
    } while (0)

#define READ_B(BF, kslice)                                               \
    do {                                                                 \
        _Pragma("unroll")                                                \
        for (int n_ = 0; n_ < 4; ++n_)                                   \
            BF[n_] = *(const bf16x8*)(pA + (n_ * 16 + l15) * 512 +       \
                                      (((kslice) * 64 + g * 16) ^ swzB));\
    } while (0)

#define MFMA_SET(slot, BF)                                               \
    do {                                                                 \
        __builtin_amdgcn_s_setprio(1);                                   \
        _Pragma("unroll")                                                \
        for (int m_ = 0; m_ < 4; ++m_)                                   \
            _Pragma("unroll")                                            \
            for (int n_ = 0; n_ < 4; ++n_)                               \
                acc[m_][n_] = __builtin_amdgcn_mfma_f32_16x16x32_bf16(   \
                    wreg[slot][m_], BF[n_], acc[m_][n_], 0, 0, 0);       \
        __builtin_amdgcn_s_setprio(0);                                   \
    } while (0)

    // ---- preload biases (plain loads; forced complete before ring primes)
    fvec4 bias[3][4];
#pragma unroll
    for (int l = 0; l < 3; ++l) {
        const float* bl = (l == 0 ? b1 : l == 1 ? b2 : b3) + s * 256;
#pragma unroll
        for (int m = 0; m < 4; ++m)
            bias[l][m] = *(const fvec4*)(bl + wv + m * 16 + g * 4);
    }

    // ---- stage b[s][row0..row0+63][:] fp32 -> bf16 into act (swizzled)
    const float* src = bIn + ((size_t)s * NB + row0) * NF;
#pragma unroll
    for (int it = 0; it < 16; ++it) {
        int flat = it * 1024 + t * 4;
        int r = flat >> 8;
        int f = flat & 255;
        fvec4 v = __builtin_nontemporal_load((const fvec4*)(src + flat));
        union { __bf16 h[4]; unsigned long long q; } pk;
        pk.h[0] = (__bf16)v[0]; pk.h[1] = (__bf16)v[1];
        pk.h[2] = (__bf16)v[2]; pk.h[3] = (__bf16)v[3];
        *(unsigned long long*)(pA + r * 512 + ((f * 2) ^ ((r & 15) << 4))) = pk.q;
    }

    // force bias values materialized HERE so no compiler vmcnt(0) lands
    // inside the ring loop (in-loop vmem must be ring loads only).
#pragma unroll
    for (int l = 0; l < 3; ++l)
#pragma unroll
        for (int m = 0; m < 4; ++m)
            asm volatile("" :: "v"(bias[l][m]));

    // ---- prime the ring: chunks 0,1,2 in flight (12 loads)
    WLOAD(0);
    WLOAD(1);
    WLOAD(2);
    BAR();   // act staged; ring loads fly over (no vmcnt drain)

#pragma unroll
    for (int l = 0; l < 3; ++l) {
        f32x4 acc[4][4];
#pragma unroll
        for (int m = 0; m < 4; ++m)
#pragma unroll
            for (int n = 0; n < 4; ++n)
                acc[m][n] = (f32x4){0.f, 0.f, 0.f, 0.f};

        bf16x8 bfX[4], bfY[4];
        READ_B(bfX, 0);

#pragma unroll
        for (int ks = 0; ks < 8; ++ks) {
            const int c = l * 8 + ks;          // chunk consumed this step
            // require chunk c arrived; up to 2 younger chunks in flight
            if (c <= 21)      asm volatile("s_waitcnt vmcnt(8)");
            else if (c == 22) asm volatile("s_waitcnt vmcnt(4)");
            else              asm volatile("s_waitcnt vmcnt(0)");
            __builtin_amdgcn_sched_barrier(0);   // rule 18: pin MFMA below

            if (ks < 7) {                        // read-ahead next act slice
                if ((ks & 1) == 0) READ_B(bfY, ks + 1);
                else               READ_B(bfX, ks + 1);
            }
            if ((ks & 1) == 0) MFMA_SET(c % 3, bfX);
            else               MFMA_SET(c % 3, bfY);

            // refill the slot just consumed (WAR via variable dependency)
            if (c + 3 <= 23) WLOAD(c + 3);
        }

        BAR();   // all act reads complete before in-place update

        // epilogue: +bias, leaky, cvt bf16, packed 8B write
#pragma unroll
        for (int m = 0; m < 4; ++m) {
            int vbyte = (wv + m * 16 + g * 4) * 2;
#pragma unroll
            for (int n = 0; n < 4; ++n) {
                union { __bf16 h[4]; unsigned long long q; } pk;
#pragma unroll
                for (int j = 0; j < 4; ++j) {
                    float x = acc[m][n][j] + bias[l][m][j];
                    x = (x >= 0.f) ? x : 0.1f * x;
                    pk.h[j] = (__bf16)x;
                }
                *(unsigned long long*)(pA + (n * 16 + l15) * 512 + (vbyte ^ swzB)) = pk.q;
            }
        }
        BAR();
    }

    // ---- layer 4: A_s[row] = dot(act3[row], w4[s]) + b4[s] -> partial P
    const int r4   = t >> 2;
    const int u0   = (t & 3) * 64;
    const int swz4 = (r4 & 15) << 4;
    const float* w4s = W4 + s * 256 + u0;
    float part = 0.f;
#pragma unroll
    for (int i = 0; i < 8; ++i) {
        bf16x8 x = *(const bf16x8*)(pA + r4 * 512 + (((u0 + i * 8) * 2) ^ swz4));
        fvec4 wlo = *(const fvec4*)(w4s + i * 8);
        fvec4 whi = *(const fvec4*)(w4s + i * 8 + 4);
        part += (float)x[0] * wlo[0] + (float)x[1] * wlo[1] +
                (float)x[2] * wlo[2] + (float)x[3] * wlo[3] +
                (float)x[4] * whi[0] + (float)x[5] * whi[1] +
                (float)x[6] * whi[2] + (float)x[7] * whi[3];
    }
    part += __shfl_xor(part, 1);
    part += __shfl_xor(part, 2);
    if ((t & 3) == 0) P[(size_t)s * NB + row0 + r4] = part + b4[s];
}

// ---------------------------------------------------------------------------
// Final: out[i] = sigmoid(sum_s P[s][i])
// ---------------------------------------------------------------------------
__global__ __launch_bounds__(256) void reduce_kernel(
    const float* __restrict__ P, float* __restrict__ out)
{
    int i = blockIdx.x * 256 + threadIdx.x;
    float a = 0.f;
#pragma unroll
    for (int sp = 0; sp < NSPEC; ++sp) a += P[(size_t)sp * NB + i];
    out[i] = 1.f / (1.f + __expf(-a));
}

extern "C" void kernel_launch(void* const* d_in, const int* in_sizes, int n_in,
                              void* d_out, int out_size, void* d_ws, size_t ws_size,
                              hipStream_t stream)
{
    const float* bIn = (const float*)d_in[0];
    const float* W1  = (const float*)d_in[1];
    const float* b1  = (const float*)d_in[2];
    const float* W2  = (const float*)d_in[3];
    const float* b2  = (const float*)d_in[4];
    const float* W3  = (const float*)d_in[5];
    const float* b3  = (const float*)d_in[6];
    const float* W4  = (const float*)d_in[7];
    const float* b4  = (const float*)d_in[8];
    __bf16* WT = (__bf16*)d_ws;                       // 3 MB
    float*  P  = (float*)((char*)d_ws + (3u << 20));  // 2 MB partials

    wconv_kernel<<<1536, 256, 0, stream>>>(W1, W2, W3, WT);
    mlp_kernel<<<8192, 256, 0, stream>>>(bIn, b1, b2, b3, W4, b4, WT, P);
    reduce_kernel<<<NB / 256, 256, 0, stream>>>(P, (float*)d_out);
}

// Round 19
// 324.831 us; speedup vs baseline: 1.8982x; 1.4105x over previous
//
#include <hip/hip_runtime.h>

typedef __bf16 bf16x8 __attribute__((ext_vector_type(8)));
typedef float  f32x4  __attribute__((ext_vector_type(4)));
typedef float  fvec4  __attribute__((ext_vector_type(4)));

#define NSPEC 8
#define NB    65536
#define NF    256

// ---------------------------------------------------------------------------
// Prologue: W[l][s][in][out] f32  ->  WT[l][s][out][in] bf16   (3 MB in d_ws)
// ---------------------------------------------------------------------------
__global__ __launch_bounds__(256) void wconv_kernel(
    const float* __restrict__ W1, const float* __restrict__ W2,
    const float* __restrict__ W3, __bf16* __restrict__ WT)
{
    __shared__ float tile[32][33];
    int bid = blockIdx.x;
    int l   = bid >> 9;
    int rem = bid & 511;
    int s   = rem >> 6;
    int tt  = rem & 63;
    int ti  = tt >> 3, tj = tt & 7;
    const float* W   = (l == 0) ? W1 : (l == 1) ? W2 : W3;
    const float* ibs = W + (size_t)s * 65536;
    int c  = threadIdx.x & 31;
    int r0 = threadIdx.x >> 5;
#pragma unroll
    for (int k = 0; k < 4; ++k) {
        int r = r0 + k * 8;
        tile[r][c] = ibs[(ti * 32 + r) * 256 + tj * 32 + c];
    }
    __syncthreads();
    __bf16* obs = WT + ((size_t)(l * 8 + s)) * 65536;
#pragma unroll
    for (int k = 0; k < 4; ++k) {
        int r = r0 + k * 8;
        obs[(tj * 32 + r) * 256 + ti * 32 + c] = (__bf16)tile[c][r];
    }
}

// async global->LDS, 16B per lane, literal size (required)
#define GLLD(gp, lp)                                                     \
    __builtin_amdgcn_global_load_lds(                                    \
        (const __attribute__((address_space(1))) char*)(gp),             \
        (__attribute__((address_space(3))) char*)(lp), 16, 0, 0)

// full barrier WITHOUT vmcnt drain: weight prefetch survives.
#define BAR()                                                            \
    do {                                                                 \
        __builtin_amdgcn_sched_barrier(0);                               \
        asm volatile("s_waitcnt lgkmcnt(0)" ::: "memory");               \
        __builtin_amdgcn_s_barrier();                                    \
        __builtin_amdgcn_sched_barrier(0);                               \
    } while (0)

// ---------------------------------------------------------------------------
// Fused MLP = r15-best (328us) with ONE change: species = blockIdx & 7.
// With round-robin block->XCD dispatch, all blocks of species s land on
// XCD s, so each XCD's L2 only caches ITS species' 384KB of weights ->
// weight stream becomes L2-resident instead of hammering L3 at ~9.5 TB/s
// (8192 blocks x 384KB re-fetch). T1 adapted: same-L2 co-location.
// ---------------------------------------------------------------------------
__global__ __launch_bounds__(256, 2) void mlp_kernel(
    const float* __restrict__ bIn, const float* __restrict__ b1,
    const float* __restrict__ b2,  const float* __restrict__ b3,
    const float* __restrict__ W4,  const float* __restrict__ b4,
    const __bf16* __restrict__ WT, float* __restrict__ P)
{
    __shared__ __align__(16) __bf16 act[64 * 256];   // 32 KB act, in-place
    __shared__ __align__(16) char  wlds[3][16384];   // 3 x 16KB weight chunks

    const int t    = threadIdx.x;
    const int lane = t & 63;
    const int wave = t >> 6;          // 0..3, owns v-range [wave*64, wave*64+64)
    const int l15  = lane & 15;
    const int g    = lane >> 4;       // 0..3
    const int wv   = wave * 64;
    const int s    = blockIdx.x & 7;          // species -> XCD pinning
    const int row0 = (blockIdx.x >> 3) * 64;  // tile
    const int swzB = l15 << 4;
    char* const pA = (char*)act;

    // per-lane global byte offsets: instr i covers v = wv+i*16+lane/4,
    // slot lane&3 holds global quarter q = slot ^ ((v>>1)&3) (same 64B line).
    int gll_off[4];
#pragma unroll
    for (int i = 0; i < 4; ++i) {
        int v = wv + i * 16 + (lane >> 2);
        int q = (lane & 3) ^ ((v >> 1) & 3);
        gll_off[i] = v * 512 + q * 16;
    }

    const char* const wt0 = (const char*)(WT + ((size_t)(0 * 8 + s) << 16));
    const char* const wt1 = (const char*)(WT + ((size_t)(1 * 8 + s) << 16));
    const char* const wt2 = (const char*)(WT + ((size_t)(2 * 8 + s) << 16));

#define ISSUE_CHUNK(wtb, gci)                                            \
    do {                                                                 \
        char* lp0 = (char*)&wlds[(gci) % 3][wave * 4096];                \
        GLLD((wtb) + gll_off[0] + ((gci) & 7) * 64, lp0);                \
        GLLD((wtb) + gll_off[1] + ((gci) & 7) * 64, lp0 + 1024);         \
        GLLD((wtb) + gll_off[2] + ((gci) & 7) * 64, lp0 + 2048);         \
        GLLD((wtb) + gll_off[3] + ((gci) & 7) * 64, lp0 + 3072);         \
    } while (0)

#define READ_SET(AF, BF, gci, kslice)                                    \
    do {                                                                 \
        const char* wbuf_ = (const char*)wlds[(gci) % 3];                \
        _Pragma("unroll")                                                \
        for (int m_ = 0; m_ < 4; ++m_) {                                 \
            int row_ = wv + m_ * 16 + l15;                               \
            AF[m_] = *(const bf16x8*)(wbuf_ + row_ * 64 +                \
                                      ((g ^ ((row_ >> 1) & 3)) << 4));   \
        }                                                                \
        _Pragma("unroll")                                                \
        for (int n_ = 0; n_ < 4; ++n_)                                   \
            BF[n_] = *(const bf16x8*)(pA + (n_ * 16 + l15) * 512 +       \
                                      (((kslice) * 64 + g * 16) ^ swzB));\
    } while (0)

#define MFMA_SET(AF, BF)                                                 \
    do {                                                                 \
        __builtin_amdgcn_s_setprio(1);                                   \
        _Pragma("unroll")                                                \
        for (int m_ = 0; m_ < 4; ++m_)                                   \
            _Pragma("unroll")                                            \
            for (int n_ = 0; n_ < 4; ++n_)                               \
                acc[m_][n_] = __builtin_amdgcn_mfma_f32_16x16x32_bf16(   \
                    AF[m_], BF[n_], acc[m_][n_], 0, 0, 0);               \
        __builtin_amdgcn_s_setprio(0);                                   \
    } while (0)

    // ---- preload biases for all 3 layers (loop vmem must be glls only)
    fvec4 bias[3][4];
#pragma unroll
    for (int l = 0; l < 3; ++l) {
        const float* bl = (l == 0 ? b1 : l == 1 ? b2 : b3) + s * 256;
#pragma unroll
        for (int m = 0; m < 4; ++m)
            bias[l][m] = *(const fvec4*)(bl + wv + m * 16 + g * 4);
    }

    // ---- stage b[s][row0..row0+63][:] fp32 -> bf16 into act (swizzled)
    const float* src = bIn + ((size_t)s * NB + row0) * NF;
#pragma unroll
    for (int it = 0; it < 16; ++it) {
        int flat = it * 1024 + t * 4;
        int r = flat >> 8;
        int f = flat & 255;
        fvec4 v = __builtin_nontemporal_load((const fvec4*)(src + flat));
        union { __bf16 h[4]; unsigned long long q; } pk;
        pk.h[0] = (__bf16)v[0]; pk.h[1] = (__bf16)v[1];
        pk.h[2] = (__bf16)v[2]; pk.h[3] = (__bf16)v[3];
        *(unsigned long long*)(pA + r * 512 + ((f * 2) ^ ((r & 15) << 4))) = pk.q;
    }

    // ---- prime the weight pipeline: 3 chunks in flight
    ISSUE_CHUNK(wt0, 0);
    ISSUE_CHUNK(wt0, 1);
    ISSUE_CHUNK(wt0, 2);
    BAR();   // act ready; glls fly over (no vmcnt drain)

#pragma unroll
    for (int l = 0; l < 3; ++l) {
        const int c0 = l * 8;
        f32x4 acc[4][4];
#pragma unroll
        for (int m = 0; m < 4; ++m)
#pragma unroll
            for (int n = 0; n < 4; ++n)
                acc[m][n] = (f32x4){0.f, 0.f, 0.f, 0.f};

        // layer prologue: chunk c0 arrived (up to 2 more outstanding)
        bf16x8 afX[4], bfX[4], afY[4], bfY[4];
        asm volatile("s_waitcnt vmcnt(8)" ::: "memory");
        READ_SET(afX, bfX, c0, 0);

#pragma unroll
        for (int ks = 0; ks < 8; ++ks) {
            const int c = c0 + ks;             // chunk consumed this step
            if (ks < 7) {
                // read NEXT step's fragments (chunk c+1 must have arrived;
                // chunk c+2 may stay in flight)
                if (c <= 21) asm volatile("s_waitcnt vmcnt(4)" ::: "memory");
                else         asm volatile("s_waitcnt vmcnt(0)" ::: "memory");
                if ((ks & 1) == 0) READ_SET(afY, bfY, c + 1, ks + 1);
                else               READ_SET(afX, bfX, c + 1, ks + 1);
                // counted guard: allow the 8 just-issued reads outstanding,
                // require chunk c's reads (last step) retired
                asm volatile("s_waitcnt lgkmcnt(8)" ::: "memory");
            } else {
                asm volatile("s_waitcnt lgkmcnt(0)" ::: "memory");
            }
            const int gci = c + 3;             // refill buf c%3 (now safe)
            if (gci <= 23) {
                const char* wtc = (gci < 8) ? wt0 : (gci < 16) ? wt1 : wt2;
                ISSUE_CHUNK(wtc, gci);
            }
            __builtin_amdgcn_sched_barrier(0);
            // MFMAs on the set read LAST step: operands long since in regs
            if ((ks & 1) == 0) MFMA_SET(afX, bfX);
            else               MFMA_SET(afY, bfY);
            __builtin_amdgcn_sched_barrier(0);
        }

        BAR();   // all act reads complete before in-place update

        // epilogue: +bias, leaky, cvt bf16, packed 8B write
#pragma unroll
        for (int m = 0; m < 4; ++m) {
            int vbyte = (wv + m * 16 + g * 4) * 2;
#pragma unroll
            for (int n = 0; n < 4; ++n) {
                union { __bf16 h[4]; unsigned long long q; } pk;
#pragma unroll
                for (int j = 0; j < 4; ++j) {
                    float x = acc[m][n][j] + bias[l][m][j];
                    x = (x >= 0.f) ? x : 0.1f * x;
                    pk.h[j] = (__bf16)x;
                }
                *(unsigned long long*)(pA + (n * 16 + l15) * 512 + (vbyte ^ swzB)) = pk.q;
            }
        }
        BAR();
    }

    // ---- layer 4: A_s[row] = dot(act3[row], w4[s]) + b4[s] -> partial P
    const int r4   = t >> 2;
    const int u0   = (t & 3) * 64;
    const int swz4 = (r4 & 15) << 4;
    const float* w4s = W4 + s * 256 + u0;
    float part = 0.f;
#pragma unroll
    for (int i = 0; i < 8; ++i) {
        bf16x8 x = *(const bf16x8*)(pA + r4 * 512 + (((u0 + i * 8) * 2) ^ swz4));
        fvec4 wlo = *(const fvec4*)(w4s + i * 8);
        fvec4 whi = *(const fvec4*)(w4s + i * 8 + 4);
        part += (float)x[0] * wlo[0] + (float)x[1] * wlo[1] +
                (float)x[2] * wlo[2] + (float)x[3] * wlo[3] +
                (float)x[4] * whi[0] + (float)x[5] * whi[1] +
                (float)x[6] * whi[2] + (float)x[7] * whi[3];
    }
    part += __shfl_xor(part, 1);
    part += __shfl_xor(part, 2);
    if ((t & 3) == 0) P[(size_t)s * NB + row0 + r4] = part + b4[s];
}

// ---------------------------------------------------------------------------
// Final: out[i] = sigmoid(sum_s P[s][i])
// ---------------------------------------------------------------------------
__global__ __launch_bounds__(256) void reduce_kernel(
    const float* __restrict__ P, float* __restrict__ out)
{
    int i = blockIdx.x * 256 + threadIdx.x;
    float a = 0.f;
#pragma unroll
    for (int sp = 0; sp < NSPEC; ++sp) a += P[(size_t)sp * NB + i];
    out[i] = 1.f / (1.f + __expf(-a));
}

extern "C" void kernel_launch(void* const* d_in, const int* in_sizes, int n_in,
                              void* d_out, int out_size, void* d_ws, size_t ws_size,
                              hipStream_t stream)
{
    const float* bIn = (const float*)d_in[0];
    const float* W1  = (const float*)d_in[1];
    const float* b1  = (const float*)d_in[2];
    const float* W2  = (const float*)d_in[3];
    const float* b2  = (const float*)d_in[4];
    const float* W3  = (const float*)d_in[5];
    const float* b3  = (const float*)d_in[6];
    const float* W4  = (const float*)d_in[7];
    const float* b4  = (const float*)d_in[8];
    __bf16* WT = (__bf16*)d_ws;                       // 3 MB
    float*  P  = (float*)((char*)d_ws + (3u << 20));  // 2 MB partials

    wconv_kernel<<<1536, 256, 0, stream>>>(W1, W2, W3, WT);
    mlp_kernel<<<8192, 256, 0, stream>>>(bIn, b1, b2, b3, W4, b4, WT, P);
    reduce_kernel<<<NB / 256, 256, 0, stream>>>(P, (float*)d_out);
}